// Round 6
// baseline (1031.335 us; speedup 1.0000x reference)
//
#include <hip/hip_runtime.h>
#include <stdint.h>

typedef unsigned short u16;
typedef __bf16 bf16x8 __attribute__((ext_vector_type(8)));
typedef float f32x4 __attribute__((ext_vector_type(4)));

#define DEVI __device__ __forceinline__

static constexpr int DIM = 768;
static constexpr int SEQL = 3136;   // 56*56
static constexpr int MROWS = 25088; // 8*3136
static constexpr int HEADS = 12;
static constexpr int HD = 64;
static constexpr int NW = 196;      // tokens per window
static constexpr float QSCALE = 0.125f; // 64^-0.5
// attn LDS: sK [208][64]u16 26624 + sP 4*[16][232]u16 29696 + sT 4*[16][64]f32 16384
static constexpr int ATTN_SMEM = 72704;
static constexpr int GEMM_SMEM = 131072; // 2 dbuf x (A 32KB + B 32KB)

DEVI float b2f(u16 u) { union { unsigned i; float f; } v; v.i = ((unsigned)u) << 16; return v.f; }
DEVI u16 f2b(float f) { union { float f; unsigned u; } v; v.f = f; return (u16)((v.u + 0x7FFFu + ((v.u >> 16) & 1u)) >> 16); }

DEVI void gl_lds16(const void* g, void* l) {
  __builtin_amdgcn_global_load_lds((const __attribute__((address_space(1))) void*)g,
                                   (__attribute__((address_space(3))) void*)l, 16, 0, 0);
}

// 8B-aligned global bf16x8 load (two dwordx2)
DEVI bf16x8 ldg_b8(const u16* p) {
  union { uint4 u; bf16x8 v; } r;
  const uint2* p2 = (const uint2*)p;
  uint2 lo = p2[0], hi = p2[1];
  r.u.x = lo.x; r.u.y = lo.y; r.u.z = hi.x; r.u.w = hi.y;
  return r.v;
}

// ---------------- weight transpose + f32->bf16 convert: W[K][N] -> Wt[N][K] ---------------
__global__ __launch_bounds__(256) void transpose_cvt(const float* __restrict__ in,
                                                     u16* __restrict__ out, int K, int N) {
  __shared__ float t[32][33];
  int n0 = blockIdx.x * 32, k0 = blockIdx.y * 32;
  int tx = threadIdx.x, ty = threadIdx.y; // (32,8)
  #pragma unroll
  for (int i = ty; i < 32; i += 8) t[i][tx] = in[(size_t)(k0 + i) * N + n0 + tx];
  __syncthreads();
  #pragma unroll
  for (int i = ty; i < 32; i += 8) out[(size_t)(n0 + i) * K + k0 + tx] = f2b(t[tx][i]);
}

// ---------------- rel-pos tables f32 [27][64] -> bf16 [2][32][64] (rows>=27 zero) --------
__global__ __launch_bounds__(256) void cvt_rpb(const float* __restrict__ rph,
                                               const float* __restrict__ rpw,
                                               u16* __restrict__ rpb) {
  int i = blockIdx.x * 256 + threadIdx.x;  // 0..4095
  int tbl = i >> 11, r = (i >> 6) & 31, c = i & 63;
  float v = (r < 27) ? (tbl ? rpw : rph)[r * 64 + c] : 0.f;
  rpb[i] = f2b(v);
}

// ---------------- layernorm (768 cols); REMAP=window-partition the output row ---------------
template<bool REMAP>
__global__ __launch_bounds__(256) void ln_kernel(const float* __restrict__ xin,
                                                 const float* __restrict__ g,
                                                 const float* __restrict__ bb,
                                                 u16* __restrict__ outw) {
  __shared__ float red[8];
  const int r = blockIdx.x;
  const int tid = threadIdx.x;
  const float* xr = xin + (size_t)r * DIM;
  float v0 = xr[tid], v1 = xr[tid + 256], v2 = xr[tid + 512];
  float s1 = v0 + v1 + v2;
  float s2 = v0 * v0 + v1 * v1 + v2 * v2;
  #pragma unroll
  for (int o = 32; o > 0; o >>= 1) { s1 += __shfl_down(s1, o); s2 += __shfl_down(s2, o); }
  const int l = tid & 63, w = tid >> 6;
  if (l == 0) { red[w] = s1; red[w + 4] = s2; }
  __syncthreads();
  float ts = red[0] + red[1] + red[2] + red[3];
  float tss = red[4] + red[5] + red[6] + red[7];
  float mean = ts * (1.f / 768.f);
  float var = tss * (1.f / 768.f) - mean * mean;
  float rstd = rsqrtf(var + 1e-5f);
  size_t orow;
  if constexpr (REMAP) {
    int b = r / SEQL, s = r % SEQL;
    int h = s / 56, ww = s % 56;
    orow = (size_t)(b * 16 + (h / 14) * 4 + (ww / 14)) * NW + (h % 14) * 14 + (ww % 14);
  } else {
    orow = (size_t)r;
  }
  u16* orp = outw + orow * DIM;
  orp[tid]       = f2b((v0 - mean) * rstd * g[tid]       + bb[tid]);
  orp[tid + 256] = f2b((v1 - mean) * rstd * g[tid + 256] + bb[tid + 256]);
  orp[tid + 512] = f2b((v2 - mean) * rstd * g[tid + 512] + bb[tid + 512]);
}

// ---------------- GEMM v2: 256x256 tile, BK=64, 8 waves (2Mx4N), dbuf + counted vmcnt ------
struct Epi {
  const float* bias;
  const float* x;   // proj: residual input (f32)
  float* outf;      // proj/fc2: f32 out (d_out)
  u16* q; u16* k; u16* v; // qkv outputs (v is transposed: [wh][64][196])
  u16* o16;         // fc1 out
};

template<int K, int N, int EPI>
__global__ __launch_bounds__(512, 2)
void gemm2_ep(const u16* __restrict__ A, const u16* __restrict__ Bt, Epi ep) {
  extern __shared__ __align__(16) char gsm[];
  u16* const sA0 = (u16*)gsm;
  u16* const sA1 = (u16*)(gsm + 32768);
  u16* const sB0 = (u16*)(gsm + 65536);
  u16* const sB1 = (u16*)(gsm + 98304);

  constexpr int NBN = N / 256;
  constexpr int NKT = K / 64;

  const int tid = threadIdx.x;
  const int l = tid & 63, w = tid >> 6;
  const int lr = l & 15, lg = l >> 4;

  // bijective XCD swizzle (m204)
  const int nwg = gridDim.x;
  const int orig = blockIdx.x;
  const int qq = nwg >> 3, rr = nwg & 7;
  const int xcd = orig & 7, idx = orig >> 3;
  const int wg = (xcd < rr ? xcd * (qq + 1) : rr * (qq + 1) + (xcd - rr) * qq) + idx;
  const int bm = wg / NBN, bn = wg % NBN;
  const int wm = (w >> 2) * 128, wn = (w & 3) * 64;  // wave tile 128x64

  const u16* Ab = A + (size_t)bm * 256 * K;
  const u16* Bb = Bt + (size_t)bn * 256 * K;

  // staging map: pass p (0..3), thread covers row = p*64 + w*8 + (l>>3), phys slot = l&7.
  // LDS dest linear (p*8192 + tid*16); source col pre-swizzled by ^(row&7)  [rule #21]
  int asrc[4];
  #pragma unroll
  for (int p = 0; p < 4; ++p) {
    int row = p * 64 + w * 8 + (l >> 3);
    asrc[p] = row * K + (((l & 7) ^ (row & 7)) << 3);
  }

  auto stage = [&](int kt, u16* dA, u16* dB) {
    #pragma unroll
    for (int p = 0; p < 4; ++p)
      gl_lds16(Ab + asrc[p] + kt * 64, (char*)dA + p * 8192 + tid * 16);
    #pragma unroll
    for (int p = 0; p < 4; ++p)
      gl_lds16(Bb + asrc[p] + kt * 64, (char*)dB + p * 8192 + tid * 16);
  };

  f32x4 zero4 = {0.f, 0.f, 0.f, 0.f};
  f32x4 acc[8][4];
  #pragma unroll
  for (int i = 0; i < 8; ++i)
    #pragma unroll
    for (int j = 0; j < 4; ++j) acc[i][j] = zero4;

  stage(0, sA0, sB0);
  stage(1, sA1, sB1);

  const int p0 = lg ^ (lr & 7);        // phys slot for kk=0 (logical lg)
  const int p1 = p0 ^ 4;               // phys slot for kk=1 (logical 4+lg)

  for (int t = 0; t < NKT; ++t) {
    const u16* cA = (t & 1) ? sA1 : sA0;
    const u16* cB = (t & 1) ? sB1 : sB0;
    u16* nA = (t & 1) ? sA1 : sA0;     // buffer being refilled with t+2 (same parity)
    u16* nB = (t & 1) ? sB1 : sB0;

    if (t < NKT - 1) asm volatile("s_waitcnt vmcnt(8)" ::: "memory");
    else             asm volatile("s_waitcnt vmcnt(0)" ::: "memory");
    __builtin_amdgcn_s_barrier();

    // ---- kk = 0: read frags, 32 MFMA
    bf16x8 af[8], bfr[4];
    #pragma unroll
    for (int mf = 0; mf < 8; ++mf)
      af[mf] = *(const bf16x8*)(cA + (wm + mf * 16 + lr) * 64 + p0 * 8);
    #pragma unroll
    for (int nf = 0; nf < 4; ++nf)
      bfr[nf] = *(const bf16x8*)(cB + (wn + nf * 16 + lr) * 64 + p0 * 8);
    __builtin_amdgcn_s_setprio(1);
    #pragma unroll
    for (int mf = 0; mf < 8; ++mf)
      #pragma unroll
      for (int nf = 0; nf < 4; ++nf)
        acc[mf][nf] = __builtin_amdgcn_mfma_f32_16x16x32_bf16(af[mf], bfr[nf], acc[mf][nf], 0, 0, 0);
    __builtin_amdgcn_s_setprio(0);

    // ---- kk = 1: read frags
    bf16x8 ag[8], bg[4];
    #pragma unroll
    for (int mf = 0; mf < 8; ++mf)
      ag[mf] = *(const bf16x8*)(cA + (wm + mf * 16 + lr) * 64 + p1 * 8);
    #pragma unroll
    for (int nf = 0; nf < 4; ++nf)
      bg[nf] = *(const bf16x8*)(cB + (wn + nf * 16 + lr) * 64 + p1 * 8);

    // all waves done reading this buffer -> safe to overwrite with tile t+2
    asm volatile("s_waitcnt lgkmcnt(0)" ::: "memory");
    __builtin_amdgcn_sched_barrier(0);
    __builtin_amdgcn_s_barrier();
    if (t + 2 < NKT) stage(t + 2, nA, nB);

    __builtin_amdgcn_s_setprio(1);
    #pragma unroll
    for (int mf = 0; mf < 8; ++mf)
      #pragma unroll
      for (int nf = 0; nf < 4; ++nf)
        acc[mf][nf] = __builtin_amdgcn_mfma_f32_16x16x32_bf16(ag[mf], bg[nf], acc[mf][nf], 0, 0, 0);
    __builtin_amdgcn_s_setprio(0);
  }

  // ---- epilogue (wave tile 128x64 at (wm,wn)) ----
  const int mrow0 = bm * 256 + wm + lg * 4;
  const int ncol0 = bn * 256 + wn + lr;
  #pragma unroll
  for (int mf = 0; mf < 8; ++mf) {
    #pragma unroll
    for (int nf = 0; nf < 4; ++nf) {
      #pragma unroll
      for (int e = 0; e < 4; ++e) {
        int r = mrow0 + mf * 16 + e;
        int c = ncol0 + nf * 16;
        float v = acc[mf][nf][e] + ep.bias[c];
        if constexpr (EPI == 0) { // qkv scatter; v goes out transposed [wh][d][pos]
          int which = c / DIM;
          int hdc = c - which * DIM;
          int head = hdc >> 6, d = hdc & 63;
          int win = r / NW, pos = r - win * NW;
          size_t wh = (size_t)win * HEADS + head;
          if (which == 0)      ep.q[(wh * NW + pos) * HD + d] = f2b(v * QSCALE);
          else if (which == 1) ep.k[(wh * NW + pos) * HD + d] = f2b(v);
          else                 ep.v[(wh * HD + d) * NW + pos] = f2b(v);
        } else if constexpr (EPI == 1) { // proj: window-reverse + residual -> f32 d_out
          int win = r / NW, pos = r - win * NW;
          int b = win >> 4, wi = win & 15;
          int hh = (wi >> 2) * 14 + pos / 14;
          int ww = (wi & 3) * 14 + pos % 14;
          size_t orow = (size_t)b * SEQL + hh * 56 + ww;
          ep.outf[orow * DIM + c] = ep.x[orow * DIM + c] + v;
        } else if constexpr (EPI == 2) { // fc1: exact GELU -> bf16
          float gg = 0.5f * v * (1.f + erff(v * 0.70710678118654752f));
          ep.o16[(size_t)r * N + c] = f2b(gg);
        } else { // fc2: residual with d_out (x1), write f32
          size_t idxo = (size_t)r * N + c;
          ep.outf[idxo] = ep.outf[idxo] + v;
        }
      }
    }
  }
}

// ---------------- fused window attention v3: one 4-wave block per (win*head) ------------
__global__ __launch_bounds__(256, 2)
void attn_kernel(const u16* __restrict__ qbuf, const u16* __restrict__ kbuf,
                 const u16* __restrict__ vt, const u16* __restrict__ rpb,
                 u16* __restrict__ abuf) {
  extern __shared__ __align__(16) char smem[];
  u16* sK = (u16*)smem;                  // [208][64], 16B-slot s -> s^(row&7)
  u16* sP = (u16*)(smem + 26624);        // 4 x [16][232]
  float* sT = (float*)(smem + 56320);    // 4 x [16][64]: cols 0..26 h-term, 32..58 w-term

  const int tid = threadIdx.x;
  const int l = tid & 63, w = tid >> 6;
  const int lr = l & 15, lg = l >> 4;
  const int wh = blockIdx.x;             // win*12 + head
  const int win = wh / HEADS, head = wh - win * HEADS;

  const u16* Qg = qbuf + (size_t)wh * (NW * HD);
  const u16* Kg = kbuf + (size_t)wh * (NW * HD);
  const u16* Vg = vt + (size_t)wh * (HD * NW);   // [64][196]

  for (int t = tid; t < 1664; t += 256) {
    int r8 = t >> 3, c8 = t & 7;
    int s = (t & ~7) | (c8 ^ (r8 & 7));
    if (s >= 1568) s &= 1023;
    gl_lds16(Kg + s * 8, (char*)sK + t * 16);
  }
  __syncthreads();

  f32x4 zero4 = {0.f, 0.f, 0.f, 0.f};
  u16* myP = sP + w * (16 * 232);
  float* myT = sT + w * (16 * 64);

  for (int c = 0; c < 4; ++c) {
    const int chunk = w + 4 * c;
    if (chunk > 12) break;

    int qrow = chunk * 16 + lr; if (qrow > 195) qrow = 195;
    bf16x8 aq0 = *(const bf16x8*)(Qg + (size_t)qrow * HD + lg * 8);
    bf16x8 aq1 = *(const bf16x8*)(Qg + (size_t)qrow * HD + 32 + lg * 8);

    f32x4 th[2], tw[2];
    #pragma unroll
    for (int nf2 = 0; nf2 < 2; ++nf2) {
      const u16* bh = rpb + (nf2 * 16 + lr) * 64;
      const u16* bw = rpb + 2048 + (nf2 * 16 + lr) * 64;
      f32x4 a = zero4, b = zero4;
      a = __builtin_amdgcn_mfma_f32_16x16x32_bf16(aq0, *(const bf16x8*)(bh + lg * 8), a, 0, 0, 0);
      a = __builtin_amdgcn_mfma_f32_16x16x32_bf16(aq1, *(const bf16x8*)(bh + 32 + lg * 8), a, 0, 0, 0);
      b = __builtin_amdgcn_mfma_f32_16x16x32_bf16(aq0, *(const bf16x8*)(bw + lg * 8), b, 0, 0, 0);
      b = __builtin_amdgcn_mfma_f32_16x16x32_bf16(aq1, *(const bf16x8*)(bw + 32 + lg * 8), b, 0, 0, 0);
      th[nf2] = a; tw[nf2] = b;
    }
    #pragma unroll
    for (int nf2 = 0; nf2 < 2; ++nf2)
      #pragma unroll
      for (int e = 0; e < 4; ++e) {
        myT[(lg * 4 + e) * 64 + nf2 * 16 + lr]      = th[nf2][e];
        myT[(lg * 4 + e) * 64 + 32 + nf2 * 16 + lr] = tw[nf2][e];
      }

    f32x4 accs[13];
    #pragma unroll
    for (int nf = 0; nf < 13; ++nf) {
      int krow = nf * 16 + lr;
      int ksw = (krow & 7) << 3;
      bf16x8 b0 = *(const bf16x8*)(sK + krow * 64 + ((lg * 8) ^ ksw));
      bf16x8 b1 = *(const bf16x8*)(sK + krow * 64 + ((32 + lg * 8) ^ ksw));
      f32x4 cc = zero4;
      cc = __builtin_amdgcn_mfma_f32_16x16x32_bf16(aq0, b0, cc, 0, 0, 0);
      cc = __builtin_amdgcn_mfma_f32_16x16x32_bf16(aq1, b1, cc, 0, 0, 0);
      accs[nf] = cc;
    }

    int ihv[4], iwv[4];
    #pragma unroll
    for (int e = 0; e < 4; ++e) {
      int gi = chunk * 16 + lg * 4 + e;
      ihv[e] = (gi * 9363) >> 17;
      iwv[e] = gi - ihv[e] * 14;
    }
    float mrow[4] = {-3e38f, -3e38f, -3e38f, -3e38f};
    #pragma unroll
    for (int nf = 0; nf < 13; ++nf) {
      int j = nf * 16 + lr;
      int jh = (j * 9363) >> 17;
      int jw = j - jh * 14;
      #pragma unroll
      for (int e = 0; e < 4; ++e) {
        int ic = lg * 4 + e;
        float s = accs[nf][e]
                + myT[ic * 64 + ((ihv[e] - jh + 13) & 63)]
                + myT[ic * 64 + 32 + (iwv[e] - jw + 13)];
        if (nf == 12 && lr >= 4) s = -1e30f;
        accs[nf][e] = s;
        mrow[e] = fmaxf(mrow[e], s);
      }
    }
    #pragma unroll
    for (int e = 0; e < 4; ++e) {
      float v = mrow[e];
      v = fmaxf(v, __shfl_xor(v, 1)); v = fmaxf(v, __shfl_xor(v, 2));
      v = fmaxf(v, __shfl_xor(v, 4)); v = fmaxf(v, __shfl_xor(v, 8));
      mrow[e] = v;
    }
    float ssum[4] = {0.f, 0.f, 0.f, 0.f};
    #pragma unroll
    for (int nf = 0; nf < 13; ++nf)
      #pragma unroll
      for (int e = 0; e < 4; ++e) {
        float p = __expf(accs[nf][e] - mrow[e]);
        accs[nf][e] = p;
        ssum[e] += p;
      }
    #pragma unroll
    for (int e = 0; e < 4; ++e) {
      float v = ssum[e];
      v += __shfl_xor(v, 1); v += __shfl_xor(v, 2);
      v += __shfl_xor(v, 4); v += __shfl_xor(v, 8);
      ssum[e] = 1.f / v;
    }
    #pragma unroll
    for (int nf = 0; nf < 13; ++nf)
      #pragma unroll
      for (int e = 0; e < 4; ++e)
        myP[(lg * 4 + e) * 232 + nf * 16 + lr] = f2b(accs[nf][e] * ssum[e]);
    #pragma unroll
    for (int e = 0; e < 4; ++e)
      myP[(lg * 4 + e) * 232 + 208 + lr] = 0;

    f32x4 acco[4];
    #pragma unroll
    for (int nf = 0; nf < 4; ++nf) acco[nf] = zero4;
    #pragma unroll
    for (int ks = 0; ks < 7; ++ks) {
      bf16x8 ap = *(const bf16x8*)(myP + lr * 232 + ks * 32 + lg * 8);
      #pragma unroll
      for (int nf = 0; nf < 4; ++nf) {
        bf16x8 bv = ldg_b8(Vg + (size_t)(nf * 16 + lr) * NW + ks * 32 + lg * 8);
        acco[nf] = __builtin_amdgcn_mfma_f32_16x16x32_bf16(ap, bv, acco[nf], 0, 0, 0);
      }
    }
    u16* ob = abuf + (size_t)win * NW * DIM + head * HD;
    #pragma unroll
    for (int nf = 0; nf < 4; ++nf)
      #pragma unroll
      for (int e = 0; e < 4; ++e) {
        int row = chunk * 16 + lg * 4 + e;
        if (row < 196) ob[(size_t)row * DIM + nf * 16 + lr] = f2b(acco[nf][e]);
      }
  }
}

// ---------------- host launch ---------------
extern "C" void kernel_launch(void* const* d_in, const int* in_sizes, int n_in,
                              void* d_out, int out_size, void* d_ws, size_t ws_size,
                              hipStream_t stream) {
  (void)in_sizes; (void)n_in; (void)out_size; (void)ws_size;
  const float* x    = (const float*)d_in[0];
  const float* ln1s = (const float*)d_in[1];
  const float* ln1b = (const float*)d_in[2];
  const float* qkvw = (const float*)d_in[3];
  const float* qkvb = (const float*)d_in[4];
  const float* rph  = (const float*)d_in[5];
  const float* rpw  = (const float*)d_in[6];
  const float* pjw  = (const float*)d_in[7];
  const float* pjb  = (const float*)d_in[8];
  const float* ln2s = (const float*)d_in[9];
  const float* ln2b = (const float*)d_in[10];
  const float* f1w  = (const float*)d_in[11];
  const float* f1b  = (const float*)d_in[12];
  const float* f2w  = (const float*)d_in[13];
  const float* f2b_ = (const float*)d_in[14];
  float* out = (float*)d_out;

  char* ws = (char*)d_ws;
  u16* qkvwT = (u16*)ws;              // [2304][768]
  u16* projwT = qkvwT + 1769472;      // [768][768]
  u16* fc1wT  = qkvwT + 2359296;      // [3072][768]
  u16* fc2wT  = qkvwT + 4718592;      // [768][3072]
  u16* xw   = (u16*)(ws + 14155776);  // [25088][768]
  u16* qbuf = (u16*)(ws + 52690944);  // [1536][196][64]
  u16* kbuf = qbuf + 19267584;
  u16* vtb  = kbuf + 19267584;        // [1536][64][196]
  u16* h2   = (u16*)(ws + 168296448); // [25088][768]
  u16* abuf = xw;                     // alias (xw dead after qkv gemm)
  u16* h1   = xw;                     // [25088][3072] spans xw+q+k+vT regions (all dead)
  u16* rpb  = h2;                     // [2][32][64] bf16 tables; h2 written only after attn

  (void)hipFuncSetAttribute((const void*)attn_kernel,
                            hipFuncAttributeMaxDynamicSharedMemorySize, ATTN_SMEM);
  (void)hipFuncSetAttribute((const void*)gemm2_ep<768, 2304, 0>,
                            hipFuncAttributeMaxDynamicSharedMemorySize, GEMM_SMEM);
  (void)hipFuncSetAttribute((const void*)gemm2_ep<768, 768, 1>,
                            hipFuncAttributeMaxDynamicSharedMemorySize, GEMM_SMEM);
  (void)hipFuncSetAttribute((const void*)gemm2_ep<768, 3072, 2>,
                            hipFuncAttributeMaxDynamicSharedMemorySize, GEMM_SMEM);
  (void)hipFuncSetAttribute((const void*)gemm2_ep<3072, 768, 3>,
                            hipFuncAttributeMaxDynamicSharedMemorySize, GEMM_SMEM);

  dim3 tb(32, 8);
  transpose_cvt<<<dim3(2304 / 32, 768 / 32), tb, 0, stream>>>(qkvw, qkvwT, 768, 2304);
  transpose_cvt<<<dim3(768 / 32, 768 / 32),  tb, 0, stream>>>(pjw, projwT, 768, 768);
  transpose_cvt<<<dim3(3072 / 32, 768 / 32), tb, 0, stream>>>(f1w, fc1wT, 768, 3072);
  transpose_cvt<<<dim3(768 / 32, 3072 / 32), tb, 0, stream>>>(f2w, fc2wT, 3072, 768);
  cvt_rpb<<<16, 256, 0, stream>>>(rph, rpw, rpb);

  ln_kernel<true><<<MROWS, 256, 0, stream>>>(x, ln1s, ln1b, xw);

  { Epi e{}; e.bias = qkvb; e.q = qbuf; e.k = kbuf; e.v = vtb;
    gemm2_ep<768, 2304, 0><<<98 * 9, 512, GEMM_SMEM, stream>>>(xw, qkvwT, e); }

  attn_kernel<<<1536, 256, ATTN_SMEM, stream>>>(qbuf, kbuf, vtb, rpb, abuf);

  { Epi e{}; e.bias = pjb; e.x = x; e.outf = out;
    gemm2_ep<768, 768, 1><<<98 * 3, 512, GEMM_SMEM, stream>>>(abuf, projwT, e); }

  ln_kernel<false><<<MROWS, 256, 0, stream>>>(out, ln2s, ln2b, h2);

  { Epi e{}; e.bias = f1b; e.o16 = h1;
    gemm2_ep<768, 3072, 2><<<98 * 12, 512, GEMM_SMEM, stream>>>(h2, fc1wT, e); }

  { Epi e{}; e.bias = f2b_; e.outf = out;
    gemm2_ep<3072, 768, 3><<<98 * 3, 512, GEMM_SMEM, stream>>>(h1, fc2wT, e); }
}